// Round 3
// baseline (1377.458 us; speedup 1.0000x reference)
//
#include <hip/hip_runtime.h>

// SimpleAttention v3: full-line (128B) coalescing everywhere, t-tile=32.
// out[b, i*64+d, t] = sum_j softmax_j(a[i][j]) * ctx[j][d]   (per b,t)
// attentions[b,i,j,t] = p[j] + (i==j ? 0 : p[j+32])

typedef unsigned int uint_t;

constexpr int Bq = 16, Cq = 3072, Tq = 2048;
constexpr int TT = 32;                   // t-tile (one 128B line)
constexpr int TILES = Tq / TT;           // 64
constexpr int NBLK = Bq * TILES;         // 1024
constexpr size_t ATT_OFF = (size_t)Bq * 2048 * Tq;
constexpr int CSTR = 36;                 // clds row stride (floats): 144B rows, 16B-aligned
constexpr int PSTR = 33;                 // plds row stride (floats): odd dword stride -> conflict-free

__global__ __launch_bounds__(512, 2) void attn_v3(const float* __restrict__ x,
                                                  const float* __restrict__ xi,
                                                  float* __restrict__ out)
{
    __shared__ __align__(16) float clds[256 * CSTR];   // ctx chunk [row=jj*32+dd][t] 36.9KB
    __shared__ float plds[8 * 32 * PSTR];              // p chunk [jj*32+tl][i]       33.8KB

    const int b    = (int)blockIdx.x >> 6;
    const int tile = (int)blockIdx.x & (TILES - 1);
    const int tl   = (int)threadIdx.x & 31;
    const int slot = (int)threadIdx.x >> 5;            // 0..15
    const int t0   = tile * TT;

    const float* xb  = x  + (size_t)b * Cq * Tq + t0 + tl;
    const float* xib = xi + (size_t)b * Cq * Tq + t0 + tl;

    uint_t pk0[32], pk1[32];   // packed bf16 p for i0=slot, i1=slot+16

    // ---- phase A: coalesced loads (lane=t), f32 softmax, attn store, pack ----
    auto do_row = [&](int i, uint_t* pk) {
        float p[64];
#pragma unroll
        for (int j = 0; j < 32; ++j) p[j]      = xb [(size_t)(i * 96 + j) * Tq];
#pragma unroll
        for (int j = 0; j < 32; ++j) p[j + 32] = xib[(size_t)(i * 96 + j) * Tq];
        float m = p[0];
#pragma unroll
        for (int j = 1; j < 64; ++j) m = fmaxf(m, p[j]);
        float s = 0.f;
#pragma unroll
        for (int j = 0; j < 64; ++j) { p[j] = __expf(p[j] - m); s += p[j]; }
        const float inv = 1.f / s;
#pragma unroll
        for (int j = 0; j < 64; ++j) p[j] *= inv;
        float* ao = out + ATT_OFF + ((size_t)(b * 32 + i) * 32) * Tq + t0 + tl;
#pragma unroll
        for (int j = 0; j < 32; ++j) {
            float v = p[j] + ((j == i) ? 0.f : p[j + 32]);
            __builtin_nontemporal_store(v, &ao[(size_t)j * Tq]);
        }
#pragma unroll
        for (int k = 0; k < 32; ++k) {
            uint_t b0 = __float_as_uint(p[2 * k]);
            uint_t b1 = __float_as_uint(p[2 * k + 1]);
            uint_t lo = (b0 + 0x7fffu + ((b0 >> 16) & 1u)) >> 16;
            uint_t hi = (b1 + 0x7fffu + ((b1 >> 16) & 1u)) >> 16;
            pk[k] = lo | (hi << 16);
        }
    };
    do_row(slot, pk0);
    do_row(slot + 16, pk1);

    // ---- phase B: thread = (ig,dg,tl); 8i x 8d register tile; 2 d-passes x 8 j-chunks ----
    const int ig = slot & 3;                 // i = ig*8 + r
    const int dg = slot >> 2;                // d = dp*32 + dg*8 + cc
    const float* xb0  = x  + (size_t)b * Cq * Tq + t0;
    const float* xib0 = xi + (size_t)b * Cq * Tq + t0;

    float acc[8][8];
#pragma unroll
    for (int r = 0; r < 8; ++r)
#pragma unroll
        for (int cc = 0; cc < 8; ++cc) acc[r][cc] = 0.f;

    float rv[16];
    auto pf = [&](int c) {
        const int jc = c & 7, dp = c >> 3;
#pragma unroll
        for (int k = 0; k < 4; ++k) {
            int idx = (int)threadIdx.x + k * 512;     // 0..2047
            int row = idx >> 3, lg = idx & 7;         // row 0..255, lg 0..7
            int jj = row >> 5, dd = row & 31;
            int j  = jc * 8 + jj;
            int cl = ((j < 32) ? j : (j - 32)) * 96 + 32 + dp * 32 + dd;
            const float* sp = (j < 32) ? xb0 : xib0;
            const float4 v = *reinterpret_cast<const float4*>(&sp[(size_t)cl * Tq + lg * 4]);
            rv[k * 4 + 0] = v.x; rv[k * 4 + 1] = v.y;
            rv[k * 4 + 2] = v.z; rv[k * 4 + 3] = v.w;
        }
    };

    pf(0);
#pragma unroll
    for (int c = 0; c < 16; ++c) {
        // stage ctx chunk (float4, 16B-aligned rows)
#pragma unroll
        for (int k = 0; k < 4; ++k) {
            int idx = (int)threadIdx.x + k * 512;
            int row = idx >> 3, lg = idx & 7;
            *reinterpret_cast<float4*>(&clds[row * CSTR + lg * 4]) =
                make_float4(rv[k * 4], rv[k * 4 + 1], rv[k * 4 + 2], rv[k * 4 + 3]);
        }
        // stage p chunk (f32 unpacked from bf16-packed regs; static indexing via full unroll)
        {
            const int jc = c & 7;
#pragma unroll
            for (int jj = 0; jj < 8; ++jj) {
                const int j = jc * 8 + jj;
                const uint_t w0 = pk0[j >> 1], w1 = pk1[j >> 1];
                float f0 = __uint_as_float((j & 1) ? (w0 & 0xffff0000u) : (w0 << 16));
                float f1 = __uint_as_float((j & 1) ? (w1 & 0xffff0000u) : (w1 << 16));
                plds[(jj * 32 + tl) * PSTR + slot]      = f0;
                plds[(jj * 32 + tl) * PSTR + slot + 16] = f1;
            }
        }
        __syncthreads();                       // LDS chunk ready
        if (c < 15) pf(c + 1);                 // prefetch next chunk under compute

#pragma unroll
        for (int jj = 0; jj < 8; ++jj) {
            float pr[8], cv[8];
#pragma unroll
            for (int r = 0; r < 8; ++r)
                pr[r] = plds[(jj * 32 + tl) * PSTR + ig * 8 + r];
#pragma unroll
            for (int cc = 0; cc < 8; ++cc)
                cv[cc] = clds[(jj * 32 + dg * 8 + cc) * CSTR + tl];
#pragma unroll
            for (int r = 0; r < 8; ++r)
#pragma unroll
                for (int cc = 0; cc < 8; ++cc)
                    acc[r][cc] += pr[r] * cv[cc];
        }

        if (c == 7 || c == 15) {               // store finished d-half, coalesced along t
            const int dp = c >> 3;
            float* ob = out + (size_t)b * 2048 * Tq + t0 + tl;
#pragma unroll
            for (int r = 0; r < 8; ++r)
#pragma unroll
                for (int cc = 0; cc < 8; ++cc) {
                    int ch = (ig * 8 + r) * 64 + dp * 32 + dg * 8 + cc;
                    __builtin_nontemporal_store(acc[r][cc], &ob[(size_t)ch * Tq]);
                    acc[r][cc] = 0.f;
                }
        }
        __syncthreads();                       // all reads done before next stage
    }
}

extern "C" void kernel_launch(void* const* d_in, const int* in_sizes, int n_in,
                              void* d_out, int out_size, void* d_ws, size_t ws_size,
                              hipStream_t stream) {
    const float* x  = (const float*)d_in[0];
    const float* xi = (const float*)d_in[1];
    float* out = (float*)d_out;
    attn_v3<<<dim3(NBLK), dim3(512), 0, stream>>>(x, xi, out);
}

// Round 4
// 322.595 us; speedup vs baseline: 4.2699x; 4.2699x over previous
//
#include <hip/hip_runtime.h>

// SimpleAttention v4: TT=32 full-line coalescing; p in 128KB LDS (bf16-packed);
// ctx read direct global->reg (L1/L2 dedupes 4x); no register spills.
// out[b, i*64+d, t] = sum_j softmax_j(a[i][j]) * ctx[j][d]   (per b,t)
// attentions[b,i,j,t] = p[j] + (i==j ? 0 : p[j+32])

typedef unsigned int uint_t;

constexpr int Bq = 16, Cq = 3072, Tq = 2048;
constexpr int TT = 32;                   // t-tile = one 128B line
constexpr int TILES = Tq / TT;           // 64
constexpr int NBLK = Bq * TILES;         // 1024
constexpr size_t ATT_OFF = (size_t)Bq * 2048 * Tq;

__global__ __launch_bounds__(512, 2) void attn_v4(const float* __restrict__ x,
                                                  const float* __restrict__ xi,
                                                  float* __restrict__ out)
{
    // p packed bf16 pairs: word k holds (p[2k], p[2k+1]) for row i, time tl.
    // layout word-index = k*1024 + tl*32 + (i ^ ((tl&7)<<2))   -> 128 KB
    __shared__ uint_t plds[32 * 32 * 32];

    const int b    = (int)blockIdx.x >> 6;
    const int tile = (int)blockIdx.x & (TILES - 1);
    const int t0   = tile * TT;
    const int tl   = (int)threadIdx.x & 31;
    const int slot = (int)threadIdx.x >> 5;      // 0..15
    const int xw   = (tl & 7) << 2;              // word-index XOR swizzle

    const float* xb  = x  + (size_t)b * Cq * Tq + t0 + tl;
    const float* xib = xi + (size_t)b * Cq * Tq + t0 + tl;

    // ---- phase A: softmax for i = slot and slot+16, attn out, p -> LDS ----
#pragma unroll
    for (int rr = 0; rr < 2; ++rr) {
        const int i = slot + rr * 16;
        float p[64];
#pragma unroll
        for (int j = 0; j < 32; ++j) p[j]      = xb [(size_t)(i * 96 + j) * Tq];
#pragma unroll
        for (int j = 0; j < 32; ++j) p[j + 32] = xib[(size_t)(i * 96 + j) * Tq];
        float m = p[0];
#pragma unroll
        for (int j = 1; j < 64; ++j) m = fmaxf(m, p[j]);
        float s = 0.f;
#pragma unroll
        for (int j = 0; j < 64; ++j) { p[j] = __expf(p[j] - m); s += p[j]; }
        const float inv = 1.f / s;
#pragma unroll
        for (int j = 0; j < 64; ++j) p[j] *= inv;

        float* ao = out + ATT_OFF + ((size_t)(b * 32 + i) * 32) * Tq + t0 + tl;
#pragma unroll
        for (int j = 0; j < 32; ++j) {
            float v = p[j] + ((j == i) ? 0.f : p[j + 32]);
            __builtin_nontemporal_store(v, &ao[(size_t)j * Tq]);
        }
#pragma unroll
        for (int k = 0; k < 32; ++k) {
            uint_t b0 = __float_as_uint(p[2 * k]);
            uint_t b1 = __float_as_uint(p[2 * k + 1]);
            uint_t lo = (b0 + 0x7fffu + ((b0 >> 16) & 1u)) >> 16;
            uint_t hi = (b1 + 0x7fffu + ((b1 >> 16) & 1u)) >> 16;
            plds[k * 1024 + tl * 32 + (i ^ xw)] = lo | (hi << 16);
        }
    }
    __syncthreads();

    // ---- phase B: thread = (ig,dg,tl); acc 8i x 8d; dp loops d-halves ----
    const int ig = slot & 3;                     // i = ig*8 + r
    const int dg = slot >> 2;                    // d = dp*32 + dg*8 + dd
    const int pbase = tl * 32;                   // + k*1024

#pragma unroll
    for (int dp = 0; dp < 2; ++dp) {
        const int d0 = dp * 32 + dg * 8;
        const float* cx  = x  + (size_t)b * Cq * Tq + (size_t)(32 + d0) * Tq + t0 + tl;
        const float* cxi = xi + (size_t)b * Cq * Tq + (size_t)(32 + d0) * Tq + t0 + tl;

        float acc[8][8];
#pragma unroll
        for (int r = 0; r < 8; ++r)
#pragma unroll
            for (int dd = 0; dd < 8; ++dd) acc[r][dd] = 0.f;

        // j-pairs: k = 0..15 from x (j=2k,2k+1), k = 16..31 from xi
#pragma unroll 2
        for (int k = 0; k < 32; ++k) {
            const float* base = (k < 16) ? cx : cxi;
            const int kg = k & 15;               // j' = 2*kg, 2*kg+1
            const uint4 wa = *reinterpret_cast<const uint4*>(
                &plds[k * 1024 + pbase + ((ig * 8 + 0) ^ xw)]);
            const uint4 wb = *reinterpret_cast<const uint4*>(
                &plds[k * 1024 + pbase + ((ig * 8 + 4) ^ xw)]);
            float pj0[8], pj1[8];
            pj0[0] = __uint_as_float(wa.x << 16);  pj1[0] = __uint_as_float(wa.x & 0xffff0000u);
            pj0[1] = __uint_as_float(wa.y << 16);  pj1[1] = __uint_as_float(wa.y & 0xffff0000u);
            pj0[2] = __uint_as_float(wa.z << 16);  pj1[2] = __uint_as_float(wa.z & 0xffff0000u);
            pj0[3] = __uint_as_float(wa.w << 16);  pj1[3] = __uint_as_float(wa.w & 0xffff0000u);
            pj0[4] = __uint_as_float(wb.x << 16);  pj1[4] = __uint_as_float(wb.x & 0xffff0000u);
            pj0[5] = __uint_as_float(wb.y << 16);  pj1[5] = __uint_as_float(wb.y & 0xffff0000u);
            pj0[6] = __uint_as_float(wb.z << 16);  pj1[6] = __uint_as_float(wb.z & 0xffff0000u);
            pj0[7] = __uint_as_float(wb.w << 16);  pj1[7] = __uint_as_float(wb.w & 0xffff0000u);

            float c0[8], c1[8];
#pragma unroll
            for (int dd = 0; dd < 8; ++dd)
                c0[dd] = base[(size_t)(kg * 192 + dd) * Tq];
#pragma unroll
            for (int dd = 0; dd < 8; ++dd)
                c1[dd] = base[(size_t)(kg * 192 + 96 + dd) * Tq];

#pragma unroll
            for (int r = 0; r < 8; ++r)
#pragma unroll
                for (int dd = 0; dd < 8; ++dd)
                    acc[r][dd] += pj0[r] * c0[dd] + pj1[r] * c1[dd];
        }

        float* ob = out + (size_t)b * 2048 * Tq + t0 + tl;
#pragma unroll
        for (int r = 0; r < 8; ++r)
#pragma unroll
            for (int dd = 0; dd < 8; ++dd) {
                int ch = (ig * 8 + r) * 64 + d0 + dd;
                __builtin_nontemporal_store(acc[r][dd], &ob[(size_t)ch * Tq]);
            }
    }
}

extern "C" void kernel_launch(void* const* d_in, const int* in_sizes, int n_in,
                              void* d_out, int out_size, void* d_ws, size_t ws_size,
                              hipStream_t stream) {
    const float* x  = (const float*)d_in[0];
    const float* xi = (const float*)d_in[1];
    float* out = (float*)d_out;
    attn_v4<<<dim3(NBLK), dim3(512), 0, stream>>>(x, xi, out);
}

// Round 5
// 307.976 us; speedup vs baseline: 4.4726x; 1.0475x over previous
//
#include <hip/hip_runtime.h>

// SimpleAttention v5: v4 + occupancy fix — 1024-thread blocks (4 waves/SIMD),
// one softmax row per thread, single d-pass in phase B.
// out[b, i*64+d, t] = sum_j softmax_j(a[i][j]) * ctx[j][d]   (per b,t)
// attentions[b,i,j,t] = p[j] + (i==j ? 0 : p[j+32])

typedef unsigned int uint_t;

constexpr int Bq = 16, Cq = 3072, Tq = 2048;
constexpr int TT = 32;                   // t-tile = one 128B line
constexpr int TILES = Tq / TT;           // 64
constexpr int NBLK = Bq * TILES;         // 1024
constexpr size_t ATT_OFF = (size_t)Bq * 2048 * Tq;

__global__ __launch_bounds__(1024, 4) void attn_v5(const float* __restrict__ x,
                                                   const float* __restrict__ xi,
                                                   float* __restrict__ out)
{
    // p packed bf16 pairs: word k holds (p[2k], p[2k+1]) for row i, time tl.
    // word-index = k*1024 + tl*32 + (i ^ ((tl&7)<<2))   -> 128 KB
    __shared__ uint_t plds[32 * 32 * 32];

    const int b    = (int)blockIdx.x >> 6;
    const int tile = (int)blockIdx.x & (TILES - 1);
    const int t0   = tile * TT;
    const int tl   = (int)threadIdx.x & 31;
    const int slot = (int)threadIdx.x >> 5;      // 0..31
    const int xw   = (tl & 7) << 2;              // word-index XOR swizzle

    const float* xb  = x  + (size_t)b * Cq * Tq + t0 + tl;
    const float* xib = xi + (size_t)b * Cq * Tq + t0 + tl;

    // ---- phase A: softmax for row i = slot; attn out; p -> LDS ----
    {
        const int i = slot;
        float p[64];
#pragma unroll
        for (int j = 0; j < 32; ++j) p[j]      = xb [(size_t)(i * 96 + j) * Tq];
#pragma unroll
        for (int j = 0; j < 32; ++j) p[j + 32] = xib[(size_t)(i * 96 + j) * Tq];
        float m = p[0];
#pragma unroll
        for (int j = 1; j < 64; ++j) m = fmaxf(m, p[j]);
        float s = 0.f;
#pragma unroll
        for (int j = 0; j < 64; ++j) { p[j] = __expf(p[j] - m); s += p[j]; }
        const float inv = 1.f / s;
#pragma unroll
        for (int j = 0; j < 64; ++j) p[j] *= inv;

        float* ao = out + ATT_OFF + ((size_t)(b * 32 + i) * 32) * Tq + t0 + tl;
#pragma unroll
        for (int j = 0; j < 32; ++j) {
            float v = p[j] + ((j == i) ? 0.f : p[j + 32]);
            __builtin_nontemporal_store(v, &ao[(size_t)j * Tq]);
        }
#pragma unroll
        for (int k = 0; k < 32; ++k) {
            uint_t b0 = __float_as_uint(p[2 * k]);
            uint_t b1 = __float_as_uint(p[2 * k + 1]);
            uint_t lo = (b0 + 0x7fffu + ((b0 >> 16) & 1u)) >> 16;
            uint_t hi = (b1 + 0x7fffu + ((b1 >> 16) & 1u)) >> 16;
            plds[k * 1024 + tl * 32 + (i ^ xw)] = lo | (hi << 16);
        }
    }
    __syncthreads();

    // ---- phase B: thread = (ig,dg,tl); acc 8i x 8d; single d-pass ----
    const int ig = slot & 3;                     // i = ig*8 + r
    const int dg = slot >> 2;                    // d = dg*8 + dd, dg 0..7
    const int d0 = dg * 8;
    const int pbase = tl * 32;

    const float* cx  = x  + (size_t)b * Cq * Tq + (size_t)(32 + d0) * Tq + t0 + tl;
    const float* cxi = xi + (size_t)b * Cq * Tq + (size_t)(32 + d0) * Tq + t0 + tl;

    float acc[8][8];
#pragma unroll
    for (int r = 0; r < 8; ++r)
#pragma unroll
        for (int dd = 0; dd < 8; ++dd) acc[r][dd] = 0.f;

    // j-pairs: k = 0..15 from x (j=2k,2k+1), k = 16..31 from xi
#pragma unroll 2
    for (int k = 0; k < 32; ++k) {
        const float* base = (k < 16) ? cx : cxi;
        const int kg = k & 15;                   // j' = 2*kg, 2*kg+1
        const uint4 wa = *reinterpret_cast<const uint4*>(
            &plds[k * 1024 + pbase + ((ig * 8 + 0) ^ xw)]);
        const uint4 wb = *reinterpret_cast<const uint4*>(
            &plds[k * 1024 + pbase + ((ig * 8 + 4) ^ xw)]);
        float pj0[8], pj1[8];
        pj0[0] = __uint_as_float(wa.x << 16);  pj1[0] = __uint_as_float(wa.x & 0xffff0000u);
        pj0[1] = __uint_as_float(wa.y << 16);  pj1[1] = __uint_as_float(wa.y & 0xffff0000u);
        pj0[2] = __uint_as_float(wa.z << 16);  pj1[2] = __uint_as_float(wa.z & 0xffff0000u);
        pj0[3] = __uint_as_float(wa.w << 16);  pj1[3] = __uint_as_float(wa.w & 0xffff0000u);
        pj0[4] = __uint_as_float(wb.x << 16);  pj1[4] = __uint_as_float(wb.x & 0xffff0000u);
        pj0[5] = __uint_as_float(wb.y << 16);  pj1[5] = __uint_as_float(wb.y & 0xffff0000u);
        pj0[6] = __uint_as_float(wb.z << 16);  pj1[6] = __uint_as_float(wb.z & 0xffff0000u);
        pj0[7] = __uint_as_float(wb.w << 16);  pj1[7] = __uint_as_float(wb.w & 0xffff0000u);

        float c0[8], c1[8];
#pragma unroll
        for (int dd = 0; dd < 8; ++dd)
            c0[dd] = base[(size_t)(kg * 192 + dd) * Tq];
#pragma unroll
        for (int dd = 0; dd < 8; ++dd)
            c1[dd] = base[(size_t)(kg * 192 + 96 + dd) * Tq];

#pragma unroll
        for (int r = 0; r < 8; ++r)
#pragma unroll
            for (int dd = 0; dd < 8; ++dd)
                acc[r][dd] += pj0[r] * c0[dd] + pj1[r] * c1[dd];
    }

    float* ob = out + (size_t)b * 2048 * Tq + t0 + tl;
#pragma unroll
    for (int r = 0; r < 8; ++r)
#pragma unroll
        for (int dd = 0; dd < 8; ++dd) {
            int ch = (ig * 8 + r) * 64 + d0 + dd;
            __builtin_nontemporal_store(acc[r][dd], &ob[(size_t)ch * Tq]);
        }
}

extern "C" void kernel_launch(void* const* d_in, const int* in_sizes, int n_in,
                              void* d_out, int out_size, void* d_ws, size_t ws_size,
                              hipStream_t stream) {
    const float* x  = (const float*)d_in[0];
    const float* xi = (const float*)d_in[1];
    float* out = (float*)d_out;
    attn_v5<<<dim3(NBLK), dim3(1024), 0, stream>>>(x, xi, out);
}